// Round 1
// baseline (1111.755 us; speedup 1.0000x reference)
//
#include <hip/hip_runtime.h>

#define DIM 1024
#define SEQ 2048

typedef __attribute__((ext_vector_type(8))) short bf16x8;
typedef __attribute__((ext_vector_type(4))) float f32x4;
typedef __attribute__((ext_vector_type(4))) unsigned short us4;

__device__ __forceinline__ unsigned short f2bf(float f) {
    union { float f; unsigned int u; } v; v.f = f;
    unsigned int r = (v.u + 0x7FFFu + ((v.u >> 16) & 1u)) >> 16;
    return (unsigned short)r;
}

__global__ __launch_bounds__(256) void cast_f32_bf16(const float* __restrict__ src,
                                                     unsigned short* __restrict__ dst, int n) {
    int i = (blockIdx.x * 256 + threadIdx.x) * 8;
    if (i >= n) return;
    float4 a = *(const float4*)(src + i);
    float4 b = *(const float4*)(src + i + 4);
    us4 lo = { f2bf(a.x), f2bf(a.y), f2bf(a.z), f2bf(a.w) };
    us4 hi = { f2bf(b.x), f2bf(b.y), f2bf(b.z), f2bf(b.w) };
    *(us4*)(dst + i) = lo;
    *(us4*)(dst + i + 4) = hi;
}

// C[M,N] = A[M,K] * W[N,K]^T + bias, output bf16 scaled.
// A = xb [16384,1024] bf16, W = wb[bz] [1024,1024] bf16 (nn.Linear weight, row = out feature)
__global__ __launch_bounds__(256) void gemm_qkv(
    const unsigned short* __restrict__ xb,
    const unsigned short* __restrict__ wb,
    const float* __restrict__ bq, const float* __restrict__ bk, const float* __restrict__ bv,
    unsigned short* __restrict__ qb, unsigned short* __restrict__ kb, unsigned short* __restrict__ vb)
{
    __shared__ unsigned short As[128 * 32];
    __shared__ unsigned short Bs[128 * 32];
    const int bz = blockIdx.z;
    const unsigned short* W = wb + (size_t)bz * DIM * DIM;
    const float* bias = (bz == 0) ? bq : ((bz == 1) ? bk : bv);
    unsigned short* C = (bz == 0) ? qb : ((bz == 1) ? kb : vb);
    const float scale = (bz == 0) ? 0.03125f : 1.0f;   // fold 1/sqrt(1024) into q
    const int m0 = blockIdx.y * 128;
    const int n0 = blockIdx.x * 128;
    const int tid = threadIdx.x;
    const int lane = tid & 63, wid = tid >> 6;
    const int wr = wid >> 1, wc = wid & 1;

    f32x4 acc[4][4];
#pragma unroll
    for (int i = 0; i < 4; i++)
#pragma unroll
        for (int j = 0; j < 4; j++) acc[i][j] = (f32x4){0.f, 0.f, 0.f, 0.f};

    for (int kt = 0; kt < DIM; kt += 32) {
#pragma unroll
        for (int c = 0; c < 2; c++) {
            int chunk = tid * 2 + c;            // 0..511, 16B each
            int row = chunk >> 2;               // 0..127
            int q4 = chunk & 3;                 // 16B sub-chunk within 64B row
            *(bf16x8*)&As[chunk * 8] = *(const bf16x8*)&xb[(size_t)(m0 + row) * DIM + kt + q4 * 8];
            *(bf16x8*)&Bs[chunk * 8] = *(const bf16x8*)&W[(size_t)(n0 + row) * DIM + kt + q4 * 8];
        }
        __syncthreads();
        bf16x8 af[4], bf[4];
#pragma unroll
        for (int mi = 0; mi < 4; mi++) {
            int row = wr * 64 + mi * 16 + (lane & 15);
            af[mi] = *(const bf16x8*)&As[row * 32 + (lane >> 4) * 8];
        }
#pragma unroll
        for (int nj = 0; nj < 4; nj++) {
            int row = wc * 64 + nj * 16 + (lane & 15);
            bf[nj] = *(const bf16x8*)&Bs[row * 32 + (lane >> 4) * 8];
        }
#pragma unroll
        for (int mi = 0; mi < 4; mi++)
#pragma unroll
            for (int nj = 0; nj < 4; nj++)
                acc[mi][nj] = __builtin_amdgcn_mfma_f32_16x16x32_bf16(af[mi], bf[nj], acc[mi][nj], 0, 0, 0);
        __syncthreads();
    }
#pragma unroll
    for (int mi = 0; mi < 4; mi++) {
#pragma unroll
        for (int nj = 0; nj < 4; nj++) {
            int col = n0 + wc * 64 + nj * 16 + (lane & 15);
            float bcol = bias[col];
#pragma unroll
            for (int r = 0; r < 4; r++) {
                int row = m0 + wr * 64 + mi * 16 + (lane >> 4) * 4 + r;
                float v = (acc[mi][nj][r] + bcol) * scale;
                C[(size_t)row * DIM + col] = f2bf(v);
            }
        }
    }
}

// Flash attention: QBLK=32, KBLK=64, 8 waves. q pre-scaled by 1/32. out fp32.
#define QBLK 32
#define KBLK 64
#define SMEM_BYTES 160128
// layout: Qs [32][1024] bf16 swizzled @0 (65536) | VT [1024][40] bf16 swizzled @65536 (81920)
//         S [32][64] f32 @147456 (8192) | P [32][64] bf16 swizzled @155648 (4096) | stats @159744

__global__ __launch_bounds__(512) void attn_fwd(
    const unsigned short* __restrict__ qb,
    const unsigned short* __restrict__ kb,
    const unsigned short* __restrict__ vb,
    float* __restrict__ out)
{
    extern __shared__ char smem[];
    char* VTb = smem + 65536;
    float* S = (float*)(smem + 147456);
    char* Pb = smem + 155648;
    float* mrow = (float*)(smem + 159744);
    float* lrow = mrow + 32;
    float* frow = mrow + 64;

    const int nb = blockIdx.x;
    const int b = nb & 7;            // batch == XCD id -> K/V L2 locality
    const int qt = nb >> 3;          // 0..63
    const int tid = threadIdx.x;
    const int lane = tid & 63, wid = tid >> 6;

    const unsigned short* Qg = qb + ((size_t)b * SEQ + qt * QBLK) * DIM;
    const unsigned short* Kg = kb + (size_t)b * SEQ * DIM;
    const unsigned short* Vg = vb + (size_t)b * SEQ * DIM;
    float* Og = out + ((size_t)b * SEQ + qt * QBLK) * DIM;

    // stage Q tile (swizzled rows: byte_off ^= (row&7)<<4)
#pragma unroll
    for (int c = 0; c < 8; c++) {
        int chunk = c * 512 + tid;           // 0..4095 x 16B
        int byte = chunk * 16;
        int row = byte >> 11;
        int off = byte & 2047;
        *(bf16x8*)(smem + row * 2048 + (off ^ ((row & 7) << 4))) =
            *(const bf16x8*)((const char*)Qg + byte);
    }
    if (tid < 32) { mrow[tid] = -1e30f; lrow[tid] = 0.0f; }

    const int wr = wid >> 2, wc = wid & 3;   // QK: 2x4 waves over 32x64 score tile
    f32x4 o[2][8];
#pragma unroll
    for (int i = 0; i < 2; i++)
#pragma unroll
        for (int j = 0; j < 8; j++) o[i][j] = (f32x4){0.f, 0.f, 0.f, 0.f};

    __syncthreads();

    for (int kt = 0; kt < SEQ; kt += KBLK) {
        // ---- QK^T: each wave one 16x16 fragment, K-loop over D=1024 ----
        f32x4 sacc = (f32x4){0.f, 0.f, 0.f, 0.f};
        const int qrow = wr * 16 + (lane & 15);
        const char* Qrow = smem + qrow * 2048;
        const int qsw = (qrow & 7) << 4;
        const unsigned short* Krow = Kg + (size_t)(kt + wc * 16 + (lane & 15)) * DIM + (lane >> 4) * 8;
#pragma unroll 8
        for (int kk = 0; kk < 32; kk++) {
            bf16x8 a = *(const bf16x8*)(Qrow + ((kk * 64 + (lane >> 4) * 16) ^ qsw));
            bf16x8 bb = *(const bf16x8*)(Krow + kk * 32);
            sacc = __builtin_amdgcn_mfma_f32_16x16x32_bf16(a, bb, sacc, 0, 0, 0);
        }
#pragma unroll
        for (int r = 0; r < 4; r++)
            S[(wr * 16 + (lane >> 4) * 4 + r) * 64 + wc * 16 + (lane & 15)] = sacc[r];
        __syncthreads();

        // ---- online softmax: 16 threads per row ----
        {
            const int row = tid >> 4;
            const int j = tid & 15;
            float4 sv = *(float4*)&S[row * 64 + j * 4];
            float pm = fmaxf(fmaxf(sv.x, sv.y), fmaxf(sv.z, sv.w));
#pragma unroll
            for (int m = 1; m <= 8; m <<= 1) pm = fmaxf(pm, __shfl_xor(pm, m, 64));
            float mold = mrow[row];
            float mnew = fmaxf(mold, pm);
            float p0 = __expf(sv.x - mnew), p1 = __expf(sv.y - mnew);
            float p2 = __expf(sv.z - mnew), p3 = __expf(sv.w - mnew);
            float ps = p0 + p1 + p2 + p3;
#pragma unroll
            for (int m = 1; m <= 8; m <<= 1) ps += __shfl_xor(ps, m, 64);
            float fac = __expf(mold - mnew);
            if (j == 0) {
                mrow[row] = mnew;
                lrow[row] = lrow[row] * fac + ps;
                frow[row] = fac;
            }
            us4 pu = { f2bf(p0), f2bf(p1), f2bf(p2), f2bf(p3) };
            *(us4*)(Pb + ((row * 128 + j * 8) ^ ((row & 7) << 4))) = pu;
        }
        __syncthreads();

        // ---- rescale O ----
#pragma unroll
        for (int mi = 0; mi < 2; mi++)
#pragma unroll
            for (int r = 0; r < 4; r++) {
                float f = frow[mi * 16 + (lane >> 4) * 4 + r];
#pragma unroll
                for (int nf = 0; nf < 8; nf++) o[mi][nf][r] *= f;
            }

        // ---- PV in two 32-key halves; V transposed into LDS [d][40] ----
#pragma unroll
        for (int kh = 0; kh < 2; kh++) {
            {
                const int kp = tid >> 5;       // 0..15 key pairs
                const int dg = tid & 31;
                const unsigned short* v0 = Vg + (size_t)(kt + kh * 32 + kp * 2) * DIM;
                const unsigned short* v1 = v0 + DIM;
#pragma unroll
                for (int c = 0; c < 4; c++) {
                    int d0 = dg * 8 + c * 256;
                    bf16x8 x0 = *(const bf16x8*)(v0 + d0);
                    bf16x8 x1 = *(const bf16x8*)(v1 + d0);
#pragma unroll
                    for (int i = 0; i < 8; i++) {
                        int d = d0 + i;
                        unsigned int pair = ((unsigned int)(unsigned short)x0[i]) |
                                            (((unsigned int)(unsigned short)x1[i]) << 16);
                        *(unsigned int*)(VTb + d * 80 + ((kp * 4) ^ ((d & 24) << 1))) = pair;
                    }
                }
            }
            __syncthreads();
            bf16x8 pf[2];
#pragma unroll
            for (int mi = 0; mi < 2; mi++) {
                int prow = mi * 16 + (lane & 15);
                pf[mi] = *(const bf16x8*)(Pb + prow * 128 + ((kh * 64 + (lane >> 4) * 16) ^ ((prow & 7) << 4)));
            }
#pragma unroll
            for (int nf = 0; nf < 8; nf++) {
                int d = wid * 128 + nf * 16 + (lane & 15);
                bf16x8 vf = *(const bf16x8*)(VTb + d * 80 + (((lane >> 4) * 16) ^ ((d & 24) << 1)));
#pragma unroll
                for (int mi = 0; mi < 2; mi++)
                    o[mi][nf] = __builtin_amdgcn_mfma_f32_16x16x32_bf16(pf[mi], vf, o[mi][nf], 0, 0, 0);
            }
            __syncthreads();
        }
    }

    // ---- epilogue: divide by softmax denom, write fp32 ----
#pragma unroll
    for (int mi = 0; mi < 2; mi++)
#pragma unroll
        for (int r = 0; r < 4; r++) {
            int row = mi * 16 + (lane >> 4) * 4 + r;
            float inv = 1.0f / lrow[row];
#pragma unroll
            for (int nf = 0; nf < 8; nf++) {
                int col = wid * 128 + nf * 16 + (lane & 15);
                Og[(size_t)row * DIM + col] = o[mi][nf][r] * inv;
            }
        }
}

extern "C" void kernel_launch(void* const* d_in, const int* in_sizes, int n_in,
                              void* d_out, int out_size, void* d_ws, size_t ws_size,
                              hipStream_t stream) {
    const float* x  = (const float*)d_in[0];
    const float* Wq = (const float*)d_in[1];
    const float* bq = (const float*)d_in[2];
    const float* Wk = (const float*)d_in[3];
    const float* bk = (const float*)d_in[4];
    const float* Wv = (const float*)d_in[5];
    const float* bv = (const float*)d_in[6];
    float* out = (float*)d_out;
    char* ws = (char*)d_ws;

    unsigned short* xb = (unsigned short*)(ws);                 // 32 MiB
    unsigned short* wb = (unsigned short*)(ws + 33554432);      // 6 MiB (3 weights)
    unsigned short* qb = (unsigned short*)(ws + 39845888);      // 32 MiB
    unsigned short* kb = (unsigned short*)(ws + 73400320);      // 32 MiB
    unsigned short* vb = (unsigned short*)(ws + 106954752);     // 32 MiB

    cast_f32_bf16<<<dim3(8192), 256, 0, stream>>>(x, xb, 16777216);
    cast_f32_bf16<<<dim3(512), 256, 0, stream>>>(Wq, wb, 1048576);
    cast_f32_bf16<<<dim3(512), 256, 0, stream>>>(Wk, wb + 1048576, 1048576);
    cast_f32_bf16<<<dim3(512), 256, 0, stream>>>(Wv, wb + 2097152, 1048576);

    gemm_qkv<<<dim3(8, 128, 3), 256, 0, stream>>>(xb, wb, bq, bk, bv, qb, kb, vb);

    hipFuncSetAttribute((const void*)attn_fwd, hipFuncAttributeMaxDynamicSharedMemorySize, SMEM_BYTES);
    attn_fwd<<<dim3(512), 512, SMEM_BYTES, stream>>>(qb, kb, vb, out);
}

// Round 2
// 414.339 us; speedup vs baseline: 2.6832x; 2.6832x over previous
//
#include <hip/hip_runtime.h>

#define DIM 1024
#define SEQ 2048

typedef __attribute__((ext_vector_type(8))) short bf16x8;
typedef __attribute__((ext_vector_type(4))) float f32x4;
typedef __attribute__((ext_vector_type(4))) unsigned short us4;
typedef __attribute__((ext_vector_type(4))) _Float16 h4;

__device__ __forceinline__ unsigned short f2bf(float f) {
    union { float f; unsigned int u; } v; v.f = f;
    unsigned int r = (v.u + 0x7FFFu + ((v.u >> 16) & 1u)) >> 16;
    return (unsigned short)r;
}

#define GLOAD(gp, lp) __builtin_amdgcn_global_load_lds( \
    (const __attribute__((address_space(1))) unsigned int*)(gp), \
    (__attribute__((address_space(3))) unsigned int*)(lp), 16, 0, 0)

__global__ __launch_bounds__(256) void cast_f32_bf16(const float* __restrict__ src,
                                                     unsigned short* __restrict__ dst, int n) {
    int i = (blockIdx.x * 256 + threadIdx.x) * 8;
    if (i >= n) return;
    float4 a = *(const float4*)(src + i);
    float4 b = *(const float4*)(src + i + 4);
    us4 lo = { f2bf(a.x), f2bf(a.y), f2bf(a.z), f2bf(a.w) };
    us4 hi = { f2bf(b.x), f2bf(b.y), f2bf(b.z), f2bf(b.w) };
    *(us4*)(dst + i) = lo;
    *(us4*)(dst + i + 4) = hi;
}

// Shared 128x128xBK32 core: C += A[128,K] * B[128,K]^T, both operands row-major
// along K. Staging via global_load_lds width=16 (m97 structure, linear LDS).
// A/B pre-offset to the block's first row. lda/ldb in elements.
__device__ __forceinline__ void gemm_core(
    const unsigned short* __restrict__ A, const unsigned short* __restrict__ B,
    int lda, int ldb, int K,
    unsigned short* As, unsigned short* Bs, f32x4 acc[4][4])
{
    const int tid = threadIdx.x;
    const int lane = tid & 63, wid = tid >> 6;
    const int wr = wid >> 1, wc = wid & 1;
    const int r0 = wid * 32;                  // this wave's 32-row staging slice
    const int srow = lane >> 2;               // 0..15
    const int scol = (lane & 3) * 8;          // element offset of 16B chunk

    for (int kt = 0; kt < K; kt += 32) {
        GLOAD(A + (size_t)(r0 + srow) * lda + kt + scol,      &As[r0 * 32]);
        GLOAD(A + (size_t)(r0 + 16 + srow) * lda + kt + scol, &As[(r0 + 16) * 32]);
        GLOAD(B + (size_t)(r0 + srow) * ldb + kt + scol,      &Bs[r0 * 32]);
        GLOAD(B + (size_t)(r0 + 16 + srow) * ldb + kt + scol, &Bs[(r0 + 16) * 32]);
        __syncthreads();
        bf16x8 af[4], bfr[4];
#pragma unroll
        for (int mi = 0; mi < 4; mi++) {
            int row = wr * 64 + mi * 16 + (lane & 15);
            af[mi] = *(const bf16x8*)&As[row * 32 + (lane >> 4) * 8];
        }
#pragma unroll
        for (int nj = 0; nj < 4; nj++) {
            int row = wc * 64 + nj * 16 + (lane & 15);
            bfr[nj] = *(const bf16x8*)&Bs[row * 32 + (lane >> 4) * 8];
        }
#pragma unroll
        for (int mi = 0; mi < 4; mi++)
#pragma unroll
            for (int nj = 0; nj < 4; nj++)
                acc[mi][nj] = __builtin_amdgcn_mfma_f32_16x16x32_bf16(af[mi], bfr[nj], acc[mi][nj], 0, 0, 0);
        __syncthreads();
    }
}

#define ACC_INIT() \
    f32x4 acc[4][4]; \
    _Pragma("unroll") for (int i = 0; i < 4; i++) \
    _Pragma("unroll") for (int j = 0; j < 4; j++) acc[i][j] = (f32x4){0.f, 0.f, 0.f, 0.f};

// x[16384,1024] @ W[z][1024,1024]^T + b -> q (scaled by 1/32, bf16), k (bf16),
// vt (bf16, TRANSPOSED per batch: [B][D][S]).
__global__ __launch_bounds__(256) void gemm_qkv(
    const unsigned short* __restrict__ xb, const unsigned short* __restrict__ wb,
    const float* __restrict__ bq, const float* __restrict__ bk, const float* __restrict__ bv,
    unsigned short* __restrict__ qb, unsigned short* __restrict__ kb, unsigned short* __restrict__ vt)
{
    __shared__ unsigned short As[4096], Bs[4096];
    const int bz = blockIdx.z;
    const int m0 = blockIdx.y * 128, n0 = blockIdx.x * 128;
    const float* bias = (bz == 0) ? bq : ((bz == 1) ? bk : bv);
    ACC_INIT();
    gemm_core(xb + (size_t)m0 * DIM, wb + (size_t)bz * DIM * DIM + (size_t)n0 * DIM,
              DIM, DIM, DIM, As, Bs, acc);
    const int lane = threadIdx.x & 63, wid = threadIdx.x >> 6;
    const int wr = wid >> 1, wc = wid & 1;
    const float scale = (bz == 0) ? 0.03125f : 1.0f;
    unsigned short* C = (bz == 0) ? qb : kb;
#pragma unroll
    for (int mi = 0; mi < 4; mi++) {
#pragma unroll
        for (int nj = 0; nj < 4; nj++) {
            int col = n0 + wc * 64 + nj * 16 + (lane & 15);
            float bcol = bias[col];
#pragma unroll
            for (int r = 0; r < 4; r++) {
                int row = m0 + wr * 64 + mi * 16 + (lane >> 4) * 4 + r;
                float v = (acc[mi][nj][r] + bcol) * scale;
                if (bz < 2) {
                    C[(size_t)row * DIM + col] = f2bf(v);
                } else {
                    int b = row >> 11, s = row & 2047;
                    vt[((size_t)b << 21) + ((size_t)col << 11) + s] = f2bf(v);
                }
            }
        }
    }
}

// S[b] = q[b] * k[b]^T  (q pre-scaled), fp16 out [B][S][S]
__global__ __launch_bounds__(256) void gemm_qk(
    const unsigned short* __restrict__ qb, const unsigned short* __restrict__ kb,
    unsigned short* __restrict__ sb)
{
    __shared__ unsigned short As[4096], Bs[4096];
    const int b = blockIdx.z;
    const int m0 = blockIdx.y * 128, n0 = blockIdx.x * 128;
    ACC_INIT();
    gemm_core(qb + ((size_t)b * SEQ + m0) * DIM, kb + ((size_t)b * SEQ + n0) * DIM,
              DIM, DIM, DIM, As, Bs, acc);
    const int lane = threadIdx.x & 63, wid = threadIdx.x >> 6;
    const int wr = wid >> 1, wc = wid & 1;
    _Float16* sh = (_Float16*)sb + (size_t)b * SEQ * SEQ;
#pragma unroll
    for (int mi = 0; mi < 4; mi++)
#pragma unroll
        for (int nj = 0; nj < 4; nj++) {
            int col = n0 + wc * 64 + nj * 16 + (lane & 15);
#pragma unroll
            for (int r = 0; r < 4; r++) {
                int row = m0 + wr * 64 + mi * 16 + (lane >> 4) * 4 + r;
                sh[(size_t)row * SEQ + col] = (_Float16)acc[mi][nj][r];
            }
        }
}

// Row softmax over fp16 scores -> normalized bf16 P written IN PLACE (rows are
// 4KB in both formats). One wave per row; full row (32 f32/lane) in registers.
__global__ __launch_bounds__(256) void softmax_p(unsigned short* __restrict__ sb)
{
    const int lane = threadIdx.x & 63, wid = threadIdx.x >> 6;
    const size_t row = (size_t)blockIdx.x * 4 + wid;
    unsigned short* rp = sb + row * SEQ;
    float v[32];
#pragma unroll
    for (int j = 0; j < 8; j++) {
        h4 h = *(const h4*)(rp + (j * 64 + lane) * 4);
#pragma unroll
        for (int e = 0; e < 4; e++) v[j * 4 + e] = (float)h[e];
    }
    float m = -1e30f;
#pragma unroll
    for (int i = 0; i < 32; i++) m = fmaxf(m, v[i]);
#pragma unroll
    for (int msk = 1; msk <= 32; msk <<= 1) m = fmaxf(m, __shfl_xor(m, msk, 64));
    float s = 0.f;
#pragma unroll
    for (int i = 0; i < 32; i++) { v[i] = __expf(v[i] - m); s += v[i]; }
#pragma unroll
    for (int msk = 1; msk <= 32; msk <<= 1) s += __shfl_xor(s, msk, 64);
    float inv = 1.0f / s;
#pragma unroll
    for (int j = 0; j < 8; j++) {
        us4 pu = { f2bf(v[j * 4] * inv), f2bf(v[j * 4 + 1] * inv),
                   f2bf(v[j * 4 + 2] * inv), f2bf(v[j * 4 + 3] * inv) };
        *(us4*)(rp + (j * 64 + lane) * 4) = pu;
    }
}

// O[b] = P[b] * VT[b]^T : A = P [S][S] bf16 (lda=2048), B = VT [D][S] (ldb=2048)
__global__ __launch_bounds__(256) void gemm_pv(
    const unsigned short* __restrict__ pb, const unsigned short* __restrict__ vt,
    float* __restrict__ out)
{
    __shared__ unsigned short As[4096], Bs[4096];
    const int b = blockIdx.z;
    const int m0 = blockIdx.y * 128, n0 = blockIdx.x * 128;
    ACC_INIT();
    gemm_core(pb + ((size_t)b * SEQ + m0) * SEQ, vt + ((size_t)b * DIM + n0) * SEQ,
              SEQ, SEQ, SEQ, As, Bs, acc);
    const int lane = threadIdx.x & 63, wid = threadIdx.x >> 6;
    const int wr = wid >> 1, wc = wid & 1;
    float* O = out + (size_t)b * SEQ * DIM;
#pragma unroll
    for (int mi = 0; mi < 4; mi++)
#pragma unroll
        for (int nj = 0; nj < 4; nj++) {
            int col = n0 + wc * 64 + nj * 16 + (lane & 15);
#pragma unroll
            for (int r = 0; r < 4; r++) {
                int row = m0 + wr * 64 + mi * 16 + (lane >> 4) * 4 + r;
                O[(size_t)row * DIM + col] = acc[mi][nj][r];
            }
        }
}

extern "C" void kernel_launch(void* const* d_in, const int* in_sizes, int n_in,
                              void* d_out, int out_size, void* d_ws, size_t ws_size,
                              hipStream_t stream) {
    const float* x  = (const float*)d_in[0];
    const float* Wq = (const float*)d_in[1];
    const float* bq = (const float*)d_in[2];
    const float* Wk = (const float*)d_in[3];
    const float* bk = (const float*)d_in[4];
    const float* Wv = (const float*)d_in[5];
    const float* bv = (const float*)d_in[6];
    float* out = (float*)d_out;
    char* ws = (char*)d_ws;

    unsigned short* xb = (unsigned short*)(ws);                  // 32 MiB  x bf16
    unsigned short* wb = (unsigned short*)(ws + 33554432);       //  6 MiB  Wq|Wk|Wv bf16
    unsigned short* qb = (unsigned short*)(ws + 39845888);       // 32 MiB  q bf16 (pre-scaled)
    unsigned short* kb = (unsigned short*)(ws + 73400320);       // 32 MiB  k bf16
    unsigned short* vt = (unsigned short*)(ws + 106954752);      // 32 MiB  v^T bf16 [B][D][S]
    unsigned short* sb = (unsigned short*)(ws + 140509184);      // 64 MiB  S fp16 -> P bf16

    cast_f32_bf16<<<dim3(8192), 256, 0, stream>>>(x, xb, 16777216);
    cast_f32_bf16<<<dim3(512), 256, 0, stream>>>(Wq, wb, 1048576);
    cast_f32_bf16<<<dim3(512), 256, 0, stream>>>(Wk, wb + 1048576, 1048576);
    cast_f32_bf16<<<dim3(512), 256, 0, stream>>>(Wv, wb + 2097152, 1048576);

    gemm_qkv<<<dim3(8, 128, 3), 256, 0, stream>>>(xb, wb, bq, bk, bv, qb, kb, vt);
    gemm_qk<<<dim3(16, 16, 8), 256, 0, stream>>>(qb, kb, sb);
    softmax_p<<<dim3(4096), 256, 0, stream>>>(sb);
    gemm_pv<<<dim3(8, 16, 8), 256, 0, stream>>>(sb, vt, out);
}

// Round 3
// 331.301 us; speedup vs baseline: 3.3557x; 1.2506x over previous
//
#include <hip/hip_runtime.h>

#define DIM 1024
#define SEQ 2048

typedef __attribute__((ext_vector_type(8))) short bf16x8;
typedef __attribute__((ext_vector_type(4))) float f32x4;
typedef __attribute__((ext_vector_type(4))) unsigned short us4;
typedef __attribute__((ext_vector_type(4))) _Float16 h4;

__device__ __forceinline__ unsigned short f2bf(float f) {
    union { float f; unsigned int u; } v; v.f = f;
    unsigned int r = (v.u + 0x7FFFu + ((v.u >> 16) & 1u)) >> 16;
    return (unsigned short)r;
}

#define GLOAD(gp, lp) __builtin_amdgcn_global_load_lds( \
    (const __attribute__((address_space(1))) unsigned int*)(gp), \
    (__attribute__((address_space(3))) unsigned int*)(lp), 16, 0, 0)

__global__ __launch_bounds__(256) void cast_f32_bf16(const float* __restrict__ src,
                                                     unsigned short* __restrict__ dst, int n) {
    int i = (blockIdx.x * 256 + threadIdx.x) * 8;
    if (i >= n) return;
    float4 a = *(const float4*)(src + i);
    float4 b = *(const float4*)(src + i + 4);
    us4 lo = { f2bf(a.x), f2bf(a.y), f2bf(a.z), f2bf(a.w) };
    us4 hi = { f2bf(b.x), f2bf(b.y), f2bf(b.z), f2bf(b.w) };
    *(us4*)(dst + i) = lo;
    *(us4*)(dst + i + 4) = hi;
}

// ---------------------------------------------------------------------------
// 256x256 8-phase GEMM core: C += A[256,K] * B[256,K]^T (both row-major in K).
// 512 threads = 8 waves (2M x 4N), per-wave 128x64 output, BK=32, 4 LDS K-tile
// buffers, XOR-swizzled staging (pre-swizzled global source + swizzled reads),
// counted vmcnt(8) at odd phases, setprio around the 16-MFMA cluster.
// LDS: buf[4] x { A[256][32], B[256][32] } bf16 = 4 x 32 KiB = 128 KiB.
// ---------------------------------------------------------------------------
#define STAGE(buf, op, q, G, ld, kt) \
    GLOAD((G) + (size_t)((q) * 128 + lr) * (ld) + (kt) + csrc, \
          smem + (buf) * 32768 + (op) * 16384 + (q) * 8192 + wid * 1024)

__device__ __forceinline__ void gemm256_core(
    const unsigned short* __restrict__ A, const unsigned short* __restrict__ B,
    int lda, int ldb, int K, char* smem, f32x4 acc[8][4])
{
    const int tid = threadIdx.x;
    const int lane = tid & 63;
    const int wid = tid >> 6;
    const int wm = wid >> 2;                 // 0..1
    const int wn = wid & 3;                  // 0..3
    const int lr = tid >> 2;                 // staging local row 0..127
    const int csrc = ((tid & 3) ^ ((tid >> 3) & 3)) * 8;  // pre-swizzled src chunk

    const int niter = K >> 7;                // K / 128

    // prologue: stage bufs 0,1,2 (A,A,B,B per buf = 12 issues)
#pragma unroll
    for (int jb = 0; jb < 3; jb++) {
        STAGE(jb, 0, 0, A, lda, jb * 32); STAGE(jb, 0, 1, A, lda, jb * 32);
        STAGE(jb, 1, 0, B, ldb, jb * 32); STAGE(jb, 1, 1, B, ldb, jb * 32);
    }
    asm volatile("s_waitcnt vmcnt(8)" ::: "memory");   // buf0 landed
    __builtin_amdgcn_s_barrier();

    for (int it = 0; it < niter; ++it) {
        bf16x8 bfr[4];
#pragma unroll
        for (int p = 0; p < 8; ++p) {
            const int j = p >> 1;            // buf being consumed
            const int mh = p & 1;            // M-half of this wave's tile
            // ---- ds_read register subtile (swizzled) ----
            bf16x8 af[4];
#pragma unroll
            for (int mi = 0; mi < 4; mi++) {
                int row = wm * 128 + mh * 64 + mi * 16 + (lane & 15);
                int cr = (lane >> 4) ^ ((row >> 1) & 3);
                af[mi] = *(const bf16x8*)(smem + j * 32768 + row * 64 + cr * 16);
            }
            if (mh == 0) {
#pragma unroll
                for (int nj = 0; nj < 4; nj++) {
                    int row = wn * 64 + nj * 16 + (lane & 15);
                    int cr = (lane >> 4) ^ ((row >> 1) & 3);
                    bfr[nj] = *(const bf16x8*)(smem + j * 32768 + 16384 + row * 64 + cr * 16);
                }
            }
            // ---- stage one half (A at even phase, B at odd) of buf (j+3)&3 ----
            {
                int skt = it * 128 + (j + 3) * 32;
                if (skt < K) {
                    int sb = (j + 3) & 3;
                    if (mh == 0) { STAGE(sb, 0, 0, A, lda, skt); STAGE(sb, 0, 1, A, lda, skt); }
                    else         { STAGE(sb, 1, 0, B, ldb, skt); STAGE(sb, 1, 1, B, ldb, skt); }
                }
            }
            __builtin_amdgcn_s_barrier();
            __builtin_amdgcn_s_setprio(1);
#pragma unroll
            for (int mi = 0; mi < 4; mi++)
#pragma unroll
                for (int nj = 0; nj < 4; nj++)
                    acc[mh * 4 + mi][nj] =
                        __builtin_amdgcn_mfma_f32_16x16x32_bf16(af[mi], bfr[nj], acc[mh * 4 + mi][nj], 0, 0, 0);
            __builtin_amdgcn_s_setprio(0);
            if (mh == 1) asm volatile("s_waitcnt vmcnt(8)" ::: "memory");
            __builtin_amdgcn_s_barrier();
        }
    }
}

#define ACC_INIT() \
    f32x4 acc[8][4]; \
    _Pragma("unroll") for (int i = 0; i < 8; i++) \
    _Pragma("unroll") for (int jj = 0; jj < 4; jj++) acc[i][jj] = (f32x4){0.f, 0.f, 0.f, 0.f};

// x[16384,1024] @ W[z]^T + b -> q (x1/32), k, vt (transposed [B][D][S])
__global__ __launch_bounds__(512, 2) void gemm_qkv(
    const unsigned short* __restrict__ xb, const unsigned short* __restrict__ wb,
    const float* __restrict__ bq, const float* __restrict__ bk, const float* __restrict__ bv,
    unsigned short* __restrict__ qb, unsigned short* __restrict__ kb, unsigned short* __restrict__ vt)
{
    extern __shared__ char smem[];
    const int bz = blockIdx.z;
    const int m0 = blockIdx.y * 256, n0 = blockIdx.x * 256;
    const float* bias = (bz == 0) ? bq : ((bz == 1) ? bk : bv);
    ACC_INIT();
    gemm256_core(xb + (size_t)m0 * DIM, wb + (size_t)bz * DIM * DIM + (size_t)n0 * DIM,
                 DIM, DIM, DIM, smem, acc);
    const int lane = threadIdx.x & 63, wid = threadIdx.x >> 6;
    const int wm = wid >> 2, wn = wid & 3;
    const float scale = (bz == 0) ? 0.03125f : 1.0f;
    unsigned short* C = (bz == 0) ? qb : kb;
#pragma unroll
    for (int mig = 0; mig < 8; mig++)
#pragma unroll
        for (int nj = 0; nj < 4; nj++) {
            int col = n0 + wn * 64 + nj * 16 + (lane & 15);
            float bcol = bias[col];
#pragma unroll
            for (int r = 0; r < 4; r++) {
                int row = m0 + wm * 128 + mig * 16 + (lane >> 4) * 4 + r;
                float v = (acc[mig][nj][r] + bcol) * scale;
                if (bz < 2) {
                    C[(size_t)row * DIM + col] = f2bf(v);
                } else {
                    int b = row >> 11, s = row & 2047;
                    vt[((size_t)b << 21) + ((size_t)col << 11) + s] = f2bf(v);
                }
            }
        }
}

// S[b] = q[b] * k[b]^T (q pre-scaled), fp16 out
__global__ __launch_bounds__(512, 2) void gemm_qk(
    const unsigned short* __restrict__ qb, const unsigned short* __restrict__ kb,
    unsigned short* __restrict__ sb)
{
    extern __shared__ char smem[];
    const int b = blockIdx.z;
    const int m0 = blockIdx.y * 256, n0 = blockIdx.x * 256;
    ACC_INIT();
    gemm256_core(qb + ((size_t)b * SEQ + m0) * DIM, kb + ((size_t)b * SEQ + n0) * DIM,
                 DIM, DIM, DIM, smem, acc);
    const int lane = threadIdx.x & 63, wid = threadIdx.x >> 6;
    const int wm = wid >> 2, wn = wid & 3;
    _Float16* sh = (_Float16*)sb + (size_t)b * SEQ * SEQ;
#pragma unroll
    for (int mig = 0; mig < 8; mig++)
#pragma unroll
        for (int nj = 0; nj < 4; nj++) {
            int col = n0 + wn * 64 + nj * 16 + (lane & 15);
#pragma unroll
            for (int r = 0; r < 4; r++) {
                int row = m0 + wm * 128 + mig * 16 + (lane >> 4) * 4 + r;
                sh[(size_t)row * SEQ + col] = (_Float16)acc[mig][nj][r];
            }
        }
}

// Row softmax fp16 -> normalized bf16 P in place
__global__ __launch_bounds__(256) void softmax_p(unsigned short* __restrict__ sb)
{
    const int lane = threadIdx.x & 63, wid = threadIdx.x >> 6;
    const size_t row = (size_t)blockIdx.x * 4 + wid;
    unsigned short* rp = sb + row * SEQ;
    float v[32];
#pragma unroll
    for (int j = 0; j < 8; j++) {
        h4 h = *(const h4*)(rp + (j * 64 + lane) * 4);
#pragma unroll
        for (int e = 0; e < 4; e++) v[j * 4 + e] = (float)h[e];
    }
    float m = -1e30f;
#pragma unroll
    for (int i = 0; i < 32; i++) m = fmaxf(m, v[i]);
#pragma unroll
    for (int msk = 1; msk <= 32; msk <<= 1) m = fmaxf(m, __shfl_xor(m, msk, 64));
    float s = 0.f;
#pragma unroll
    for (int i = 0; i < 32; i++) { v[i] = __expf(v[i] - m); s += v[i]; }
#pragma unroll
    for (int msk = 1; msk <= 32; msk <<= 1) s += __shfl_xor(s, msk, 64);
    float inv = 1.0f / s;
#pragma unroll
    for (int j = 0; j < 8; j++) {
        us4 pu = { f2bf(v[j * 4] * inv), f2bf(v[j * 4 + 1] * inv),
                   f2bf(v[j * 4 + 2] * inv), f2bf(v[j * 4 + 3] * inv) };
        *(us4*)(rp + (j * 64 + lane) * 4) = pu;
    }
}

// O[b] = P[b] * VT[b]^T
__global__ __launch_bounds__(512, 2) void gemm_pv(
    const unsigned short* __restrict__ pb, const unsigned short* __restrict__ vt,
    float* __restrict__ out)
{
    extern __shared__ char smem[];
    const int b = blockIdx.z;
    const int m0 = blockIdx.y * 256, n0 = blockIdx.x * 256;
    ACC_INIT();
    gemm256_core(pb + ((size_t)b * SEQ + m0) * SEQ, vt + ((size_t)b * DIM + n0) * SEQ,
                 SEQ, SEQ, SEQ, smem, acc);
    const int lane = threadIdx.x & 63, wid = threadIdx.x >> 6;
    const int wm = wid >> 2, wn = wid & 3;
    float* O = out + (size_t)b * SEQ * DIM;
#pragma unroll
    for (int mig = 0; mig < 8; mig++)
#pragma unroll
        for (int nj = 0; nj < 4; nj++) {
            int col = n0 + wn * 64 + nj * 16 + (lane & 15);
#pragma unroll
            for (int r = 0; r < 4; r++) {
                int row = m0 + wm * 128 + mig * 16 + (lane >> 4) * 4 + r;
                O[(size_t)row * DIM + col] = acc[mig][nj][r];
            }
        }
}

extern "C" void kernel_launch(void* const* d_in, const int* in_sizes, int n_in,
                              void* d_out, int out_size, void* d_ws, size_t ws_size,
                              hipStream_t stream) {
    const float* x  = (const float*)d_in[0];
    const float* Wq = (const float*)d_in[1];
    const float* bq = (const float*)d_in[2];
    const float* Wk = (const float*)d_in[3];
    const float* bk = (const float*)d_in[4];
    const float* Wv = (const float*)d_in[5];
    const float* bv = (const float*)d_in[6];
    float* out = (float*)d_out;
    char* ws = (char*)d_ws;

    unsigned short* xb = (unsigned short*)(ws);                  // 32 MiB  x bf16
    unsigned short* wb = (unsigned short*)(ws + 33554432);       //  6 MiB  Wq|Wk|Wv bf16
    unsigned short* qb = (unsigned short*)(ws + 39845888);       // 32 MiB  q bf16 (pre-scaled)
    unsigned short* kb = (unsigned short*)(ws + 73400320);       // 32 MiB  k bf16
    unsigned short* vt = (unsigned short*)(ws + 106954752);      // 32 MiB  v^T bf16 [B][D][S]
    unsigned short* sb = (unsigned short*)(ws + 140509184);      // 64 MiB  S fp16 -> P bf16

    cast_f32_bf16<<<dim3(8192), 256, 0, stream>>>(x, xb, 16777216);
    cast_f32_bf16<<<dim3(512), 256, 0, stream>>>(Wq, wb, 1048576);
    cast_f32_bf16<<<dim3(512), 256, 0, stream>>>(Wk, wb + 1048576, 1048576);
    cast_f32_bf16<<<dim3(512), 256, 0, stream>>>(Wv, wb + 2097152, 1048576);

    hipFuncSetAttribute((const void*)gemm_qkv, hipFuncAttributeMaxDynamicSharedMemorySize, 131072);
    hipFuncSetAttribute((const void*)gemm_qk,  hipFuncAttributeMaxDynamicSharedMemorySize, 131072);
    hipFuncSetAttribute((const void*)gemm_pv,  hipFuncAttributeMaxDynamicSharedMemorySize, 131072);

    gemm_qkv<<<dim3(4, 64, 3), 512, 131072, stream>>>(xb, wb, bq, bk, bv, qb, kb, vt);
    gemm_qk<<<dim3(8, 8, 8), 512, 131072, stream>>>(qb, kb, sb);
    softmax_p<<<dim3(4096), 256, 0, stream>>>(sb);
    gemm_pv<<<dim3(4, 8, 8), 512, 131072, stream>>>(sb, vt, out);
}